// Round 1
// baseline (223.096 us; speedup 1.0000x reference)
//
#include <hip/hip_runtime.h>

#define B_   8
#define N_   2048
#define FIN  256
#define FOUT 64
#define ALPHA 0.2f

typedef __attribute__((ext_vector_type(8))) short bf16x8;
typedef __attribute__((ext_vector_type(8))) unsigned short u16x8;
typedef __attribute__((ext_vector_type(4))) unsigned short u16x4;
typedef __attribute__((ext_vector_type(4))) float f32x4;

__device__ __forceinline__ float b2f(unsigned short u) {
    union { unsigned int u; float f; } v; v.u = ((unsigned int)u) << 16; return v.f;
}
// round-to-nearest-even f32 -> bf16
__device__ __forceinline__ unsigned short f2b(float f) {
    union { float f; unsigned int u; } v; v.f = f;
    unsigned int r = v.u + 0x7FFFu + ((v.u >> 16) & 1u);
    return (unsigned short)(r >> 16);
}

// ---- Kernel 1 (fused): h-GEMM + transpose + src/dst projections ----
// v2: 1024 blocks x 16 rows (was 256 x 64) -> 4 blocks/CU, 4 waves/SIMD.
// The old 256-block launch was 1 wave/SIMD: pure latency-bound.
__global__ __launch_bounds__(256) void k_hgemm_tr(
    const float* __restrict__ x, const float* __restrict__ W,
    const float* __restrict__ bW, const float* __restrict__ asrc,
    const float* __restrict__ adst,
    unsigned short* __restrict__ hT, float* __restrict__ src, float* __restrict__ dst)
{
    __shared__ unsigned short tileT[FOUT * 20];   // [f][row], pitch 20 shorts (40B, 8B-aligned rows)
    __shared__ float as_s[FOUT], ad_s[FOUT];

    const int tid = threadIdx.x;
    const int wv = tid >> 6, lane = tid & 63;
    const int quad = lane >> 4, col = lane & 15;
    const int f = wv * 16 + col;

    if (tid < FOUT) { as_s[tid] = asrc[tid]; ad_s[tid] = adst[tid]; }

    bf16x8 Bf[8];
    #pragma unroll
    for (int kk = 0; kk < 8; ++kk) {
        bf16x8 t;
        #pragma unroll
        for (int j = 0; j < 8; ++j)
            t[j] = (short)f2b(W[(kk * 32 + quad * 8 + j) * FOUT + f]);
        Bf[kk] = t;
    }
    const float bias = bW[f];
    const int r0 = blockIdx.x * 16;
    const int b = r0 >> 11;
    const int j0b = r0 & (N_ - 1);

    f32x4 acc = {0.f, 0.f, 0.f, 0.f};
    #pragma unroll
    for (int kk = 0; kk < 8; ++kk) {
        const float* xp = x + (size_t)(r0 + col) * FIN + kk * 32 + quad * 8;
        float4 x0 = *(const float4*)xp;
        float4 x1 = *(const float4*)(xp + 4);
        bf16x8 Af;
        Af[0] = (short)f2b(x0.x); Af[1] = (short)f2b(x0.y);
        Af[2] = (short)f2b(x0.z); Af[3] = (short)f2b(x0.w);
        Af[4] = (short)f2b(x1.x); Af[5] = (short)f2b(x1.y);
        Af[6] = (short)f2b(x1.z); Af[7] = (short)f2b(x1.w);
        acc = __builtin_amdgcn_mfma_f32_16x16x32_bf16(Af, Bf[kk], acc, 0, 0, 0);
    }
    #pragma unroll
    for (int reg = 0; reg < 4; ++reg)
        tileT[f * 20 + quad * 4 + reg] = f2b(acc[reg] + bias);
    __syncthreads();

    {   // src/dst dots: 16 rows x 16 f-groups of 4
        const int i = tid >> 4, fb = (tid & 15) * 4;
        float sp = 0.f, dp = 0.f;
        #pragma unroll
        for (int k = 0; k < 4; ++k) {
            float hv = b2f(tileT[(fb + k) * 20 + i]);
            sp += hv * as_s[fb + k]; dp += hv * ad_s[fb + k];
        }
        sp += __shfl_xor(sp, 1); sp += __shfl_xor(sp, 2);
        sp += __shfl_xor(sp, 4); sp += __shfl_xor(sp, 8);
        dp += __shfl_xor(dp, 1); dp += __shfl_xor(dp, 2);
        dp += __shfl_xor(dp, 4); dp += __shfl_xor(dp, 8);
        if ((tid & 15) == 0) { src[r0 + i] = sp; dst[r0 + i] = dp; }
    }
    {   // hT writeout: 64 f x 16 cols, 8B per thread
        const int fq = tid >> 2, ic = (tid & 3) * 4;
        unsigned short* op = hT + (size_t)(b * FOUT + fq) * N_ + j0b + ic;
        *(u16x4*)op = *(const u16x4*)&tileT[fq * 20 + ic];
    }
}

// ---- Kernel 2: fused attention ----
// v2 changes vs baseline:
//  - h_s LDS staging DELETED: B-fragments (hT[f][j-slice], 16B/lane contiguous)
//    are L2-resident (256KB/batch shared by 64 blocks) and loaded straight to
//    registers, double-buffered. LDS 52KB -> 17.4KB.
//  - __syncthreads() -> "s_waitcnt lgkmcnt(0); s_barrier": only w_s needs
//    barrier ordering; register-destined global loads (adj/dst/Bf) may stay in
//    flight across barriers (compiler guards consumers with counted vmcnt).
//  - adj/dst prefetch deepened to depth-2 (issue at tile t for t+2), which the
//    non-draining barrier actually preserves (~2 tile phases > 900cy HBM lat).
#define ATT_TILE(Aa,Ab,Ac,Ad, Da,Db,Dc,Dd, BfC, BfN, BUF, JT)                          \
{                                                                                      \
    const int av[16] = {Aa.x,Aa.y,Aa.z,Aa.w, Ab.x,Ab.y,Ab.z,Ab.w,                      \
                        Ac.x,Ac.y,Ac.z,Ac.w, Ad.x,Ad.y,Ad.z,Ad.w};                     \
    const float dv[16] = {Da.x,Da.y,Da.z,Da.w, Db.x,Db.y,Db.z,Db.w,                    \
                          Dc.x,Dc.y,Dc.z,Dc.w, Dd.x,Dd.y,Dd.z,Dd.w};                   \
    u16x8 p0, p1; float ls = 0.f;                                                      \
    _Pragma("unroll")                                                                  \
    for (int k = 0; k < 16; ++k) {                                                     \
        float e = srci + dv[k];                                                        \
        e = e > 0.f ? e : ALPHA * e;                                                   \
        float wval = av[k] > 0 ? __expf(e) : 0.f;                                      \
        unsigned short wb = f2b(wval);                                                 \
        ls += b2f(wb);   /* denominator from SAME rounded weights as numerator */      \
        if (k < 8) p0[k] = wb; else p1[k - 8] = wb;                                    \
    }                                                                                  \
    lsum += ls;                                                                        \
    {   unsigned short* q = &w_s[BUF][il * 136 + jg * 16];                             \
        *(u16x8*)q = p0; *(u16x8*)(q + 8) = p1; }                                      \
    {   /* depth-2 prefetch: adj+dst for JT+2 into the just-freed set */               \
        const int jn = (((JT) + 2) & 15) * 128;                                        \
        Aa = *(const int4*)(adjbase + jn);                                             \
        Ab = *(const int4*)(adjbase + jn + 4);                                         \
        Ac = *(const int4*)(adjbase + jn + 8);                                         \
        Ad = *(const int4*)(adjbase + jn + 12);                                        \
        Da = *(const float4*)(dstbase + jn);                                           \
        Db = *(const float4*)(dstbase + jn + 4);                                       \
        Dc = *(const float4*)(dstbase + jn + 8);                                       \
        Dd = *(const float4*)(dstbase + jn + 12); }                                    \
    /* LDS-only barrier: do NOT drain vmcnt (prefetch stays in flight) */              \
    asm volatile("s_waitcnt lgkmcnt(0)\n\ts_barrier" ::: "memory");                    \
    {   /* depth-1 prefetch of next tile's B-fragments (L2 hit) */                     \
        const int jn = (((JT) + 1) & 15) * 128;                                        \
        BfN[0] = *(const bf16x8*)(hfbase + jn);                                        \
        BfN[1] = *(const bf16x8*)(hfbase + jn + 32);                                   \
        BfN[2] = *(const bf16x8*)(hfbase + jn + 64);                                   \
        BfN[3] = *(const bf16x8*)(hfbase + jn + 96); }                                 \
    _Pragma("unroll")                                                                  \
    for (int kk = 0; kk < 4; ++kk) {                                                   \
        bf16x8 A0 = *(const bf16x8*)&w_s[BUF][col * 136 + kk * 32 + quad * 8];         \
        bf16x8 A1 = *(const bf16x8*)&w_s[BUF][(16 + col) * 136 + kk * 32 + quad * 8];  \
        acc0 = __builtin_amdgcn_mfma_f32_16x16x32_bf16(A0, BfC[kk], acc0, 0, 0, 0);    \
        acc1 = __builtin_amdgcn_mfma_f32_16x16x32_bf16(A1, BfC[kk], acc1, 0, 0, 0);    \
    }                                                                                  \
}

__global__ __launch_bounds__(256) void k_attn(
    const int* __restrict__ adj, const float* __restrict__ src, const float* __restrict__ dst,
    const unsigned short* __restrict__ hT, const float* __restrict__ abp,
    float* __restrict__ out)
{
    __shared__ unsigned short w_s[2][32 * 136];
    __shared__ float src_s[32];
    __shared__ float l_s[32];

    const int tid = threadIdx.x;
    const int wv = tid >> 6, lane = tid & 63;
    const int quad = lane >> 4, col = lane & 15;
    const int b = blockIdx.x >> 6;
    const int i0 = (blockIdx.x & 63) * 32;

    if (tid < 32) src_s[tid] = src[b * N_ + i0 + tid];
    __syncthreads();

    const int il = tid >> 3, jg = tid & 7;          // w-phase: row 0..31, j-group 0..7
    const float srci = src_s[il] + abp[0];
    const int* adjbase = adj + (size_t)(b * N_ + i0 + il) * N_ + jg * 16;
    const float* dstbase = dst + b * N_ + jg * 16;
    // B-fragment base: lane (wv,quad,col) reads hT[f = wv*16+col][j0 + kk*32 + quad*8 .. +8]
    const unsigned short* hfbase = hT + (size_t)(b * FOUT + wv * 16 + col) * N_ + quad * 8;

    // prologue: adj/dst for tiles 0 and 1; B-fragments for tile 0
    int4 a0 = *(const int4*)(adjbase);
    int4 a1 = *(const int4*)(adjbase + 4);
    int4 a2 = *(const int4*)(adjbase + 8);
    int4 a3 = *(const int4*)(adjbase + 12);
    int4 a4 = *(const int4*)(adjbase + 128);
    int4 a5 = *(const int4*)(adjbase + 132);
    int4 a6 = *(const int4*)(adjbase + 136);
    int4 a7 = *(const int4*)(adjbase + 140);
    float4 d0 = *(const float4*)(dstbase);
    float4 d1 = *(const float4*)(dstbase + 4);
    float4 d2 = *(const float4*)(dstbase + 8);
    float4 d3 = *(const float4*)(dstbase + 12);
    float4 d4 = *(const float4*)(dstbase + 128);
    float4 d5 = *(const float4*)(dstbase + 132);
    float4 d6 = *(const float4*)(dstbase + 136);
    float4 d7 = *(const float4*)(dstbase + 140);
    bf16x8 bfE[4], bfO[4];
    bfE[0] = *(const bf16x8*)(hfbase);
    bfE[1] = *(const bf16x8*)(hfbase + 32);
    bfE[2] = *(const bf16x8*)(hfbase + 64);
    bfE[3] = *(const bf16x8*)(hfbase + 96);

    float lsum = 0.f;
    f32x4 acc0 = {0, 0, 0, 0}, acc1 = {0, 0, 0, 0};

    for (int it = 0; it < 8; ++it) {
        const int jt = it * 2;
        ATT_TILE(a0, a1, a2, a3, d0, d1, d2, d3, bfE, bfO, 0, jt)
        ATT_TILE(a4, a5, a6, a7, d4, d5, d6, d7, bfO, bfE, 1, jt + 1)
    }

    lsum += __shfl_xor(lsum, 1);
    lsum += __shfl_xor(lsum, 2);
    lsum += __shfl_xor(lsum, 4);
    if (jg == 0) l_s[il] = lsum;
    __syncthreads();

    #pragma unroll
    for (int m = 0; m < 2; ++m) {
        f32x4 a = m ? acc1 : acc0;
        #pragma unroll
        for (int reg = 0; reg < 4; ++reg) {
            int row = m * 16 + quad * 4 + reg;
            float l = l_s[row];
            l = l > 0.f ? l : 1.f;
            float v = a[reg] / l;
            v = v > 0.f ? v : (__expf(v) - 1.f);   // ELU(alpha=1)
            out[(size_t)(b * N_ + i0 + row) * FOUT + wv * 16 + col] = v;
        }
    }
}

extern "C" void kernel_launch(void* const* d_in, const int* in_sizes, int n_in,
                              void* d_out, int out_size, void* d_ws, size_t ws_size,
                              hipStream_t stream)
{
    const float* x    = (const float*)d_in[0];
    const int*   adj  = (const int*)d_in[1];
    const float* W    = (const float*)d_in[2];
    const float* bW   = (const float*)d_in[3];
    const float* asrc = (const float*)d_in[4];
    const float* adst = (const float*)d_in[5];
    const float* abp  = (const float*)d_in[6];
    float* out = (float*)d_out;

    char* ws = (char*)d_ws;
    unsigned short* hT = (unsigned short*)ws;                               // 2 MB
    float* src = (float*)(ws + (size_t)2 * 1024 * 1024);                    // 64 KB
    float* dst = (float*)(ws + (size_t)2 * 1024 * 1024 + 64 * 1024);        // 64 KB

    k_hgemm_tr<<<1024, 256, 0, stream>>>(x, W, bW, asrc, adst, hT, src, dst);
    k_attn<<<512, 256, 0, stream>>>(adj, src, dst, hT, abp, out);
}